// Round 9
// baseline (346.327 us; speedup 1.0000x reference)
//
#include <hip/hip_runtime.h>
#include <math.h>

#define NBATCH 512
#define TLEN   2048
#define NS     24
#define KSTART 22
#define KSTOP  23
#define MID    1024
#define L2E    1.4426950408889634f
#define LN2F   0.6931471805599453f

__device__ __forceinline__ float fexp2(float x) {
#if __has_builtin(__builtin_amdgcn_exp2f)
  return __builtin_amdgcn_exp2f(x);
#else
  return exp2f(x);
#endif
}
__device__ __forceinline__ float flog2(float x) {
#if __has_builtin(__builtin_amdgcn_logf)
  return __builtin_amdgcn_logf(x);
#else
  return __log2f(x);
#endif
}

__device__ __forceinline__ float rl(float v, int k) {
  return __int_as_float(__builtin_amdgcn_readlane(__float_as_int(v), k));
}

#define SWZ(X, IMM) __int_as_float(__builtin_amdgcn_ds_swizzle(__float_as_int(X), (IMM)))

// Chain lanes 0..23: linear-space recurrence g' = (P.g)*ef (fwd) / P^T.(g*ef) (bwd).
// Gold lanes 32..63: software-pipelined gather of the gold score for this wave's
// t-range, hidden in the chain's dependency-stall shadows.
template<bool ISB>
__device__ __forceinline__ void run_chain(
    const float* __restrict__ fb, const float* __restrict__ trans,
    const int* __restrict__ tg,
    int steps, int lenm1, int lane, int j, int je,
    float* __restrict__ outg, float* __restrict__ outc,
    float* __restrict__ sgold, int dir)
{
  const bool act = (j < NS);

  float p[NS];
  #pragma unroll
  for (int k = 0; k < NS; ++k) {
    int idx = ISB ? (k * NS + je) : (je * NS + k);
    float tv = trans[idx];
    p[k] = act ? fexp2(tv * L2E) : 0.0f;
  }

  float g;
  if (ISB) g = act ? fexp2(trans[KSTOP * NS + je] * L2E) : 0.0f;
  else     g = (j == KSTART) ? 1.0f : 0.0f;
  int cE = 0;

  auto ldf = [&](int k) -> float {
    int t = ISB ? (lenm1 - k) : k;
    t = (t < 0) ? 0 : t;
    return fb[t * NS + je];
  };

  // ---- gold pipeline state (lanes >= 32) ----
  const int li  = lane - 32;
  const int T0_ = ISB ? MID : 0;
  const unsigned R_ = (unsigned)steps;
  int   tcA = 0, tpA = 0, tcB = 0, tpB = 0, tcC = 0, tpC = 0;
  float fvA = 0.f, fvB = 0.f, fvC = 0.f, tvA = 0.f, tvB = 0.f, tvC = 0.f;
  float gs = 0.f;

  // At group GG: consume slot GG-4, gather slot GG-2 (tags loaded at GG-2),
  // issue tag loads for slot GG. 2-group slack on every load->use edge.
#define GOLDG(GG) \
  if (lane >= 32) { \
    fvC = fvB; fvB = fvA; tvC = tvB; tvB = tvA; \
    tcC = tcB; tcB = tcA; tpC = tpB; tpB = tpA; \
    unsigned vq_ = (unsigned)(32 * ((GG) - 4) + li); \
    if (vq_ < R_) gs += fvC + tvC; \
    int tq_  = T0_ + 32 * ((GG) - 2) + li; \
    int tqc_ = (tq_ < 0) ? 0 : ((tq_ > lenm1) ? lenm1 : tq_); \
    int cur_ = tcC, prev_ = (tq_ == 0) ? KSTART : tpC; \
    fvA = fb[tqc_ * NS + cur_]; \
    tvA = trans[cur_ * NS + prev_]; \
    int t0_  = T0_ + 32 * (GG) + li; \
    int t0c_ = (t0_ > lenm1) ? lenm1 : t0_; \
    tcA = tg[t0c_]; \
    tpA = tg[(t0c_ > 0) ? (t0c_ - 1) : 0]; \
  }

#define DOT24(SRC) \
  const float s0  = rl(SRC, 0),  s1  = rl(SRC, 1),  s2  = rl(SRC, 2),  s3  = rl(SRC, 3),  \
              s4  = rl(SRC, 4),  s5  = rl(SRC, 5),  s6  = rl(SRC, 6),  s7  = rl(SRC, 7),  \
              s8  = rl(SRC, 8),  s9  = rl(SRC, 9),  s10 = rl(SRC, 10), s11 = rl(SRC, 11), \
              s12 = rl(SRC, 12), s13 = rl(SRC, 13), s14 = rl(SRC, 14), s15 = rl(SRC, 15), \
              s16 = rl(SRC, 16), s17 = rl(SRC, 17), s18 = rl(SRC, 18), s19 = rl(SRC, 19), \
              s20 = rl(SRC, 20), s21 = rl(SRC, 21), s22 = rl(SRC, 22), s23 = rl(SRC, 23); \
  __builtin_amdgcn_sched_barrier(0); \
  y0 = p[0] * s0;              y1 = p[1] * s1;              y2 = p[2] * s2;              y3 = p[3] * s3; \
  y0 = fmaf(p[4],  s4,  y0);   y1 = fmaf(p[5],  s5,  y1);   y2 = fmaf(p[6],  s6,  y2);   y3 = fmaf(p[7],  s7,  y3); \
  y0 = fmaf(p[8],  s8,  y0);   y1 = fmaf(p[9],  s9,  y1);   y2 = fmaf(p[10], s10, y2);   y3 = fmaf(p[11], s11, y3); \
  y0 = fmaf(p[12], s12, y0);   y1 = fmaf(p[13], s13, y1);   y2 = fmaf(p[14], s14, y2);   y3 = fmaf(p[15], s15, y3); \
  y0 = fmaf(p[16], s16, y0);   y1 = fmaf(p[17], s17, y1);   y2 = fmaf(p[18], s18, y2);   y3 = fmaf(p[19], s19, y3); \
  y0 = fmaf(p[20], s20, y0);   y1 = fmaf(p[21], s21, y1);   y2 = fmaf(p[22], s22, y2);   y3 = fmaf(p[23], s23, y3);

#define STEP1(EU) { float y0, y1, y2, y3; \
    if constexpr (ISB) { float m = g * (EU); DOT24(m); g = (y0 + y1) + (y2 + y3); } \
    else               { DOT24(g); g = ((y0 + y1) + (y2 + y3)) * (EU); } }

#define RENORM { int b0_ = __builtin_amdgcn_readlane(__float_as_int(g), 0); \
    int er_ = (b0_ >> 23) & 0xFF; int E_ = (er_ == 0) ? 0 : (er_ - 127); \
    cE += E_; g *= __int_as_float((127 - E_) << 23); }

  // ---- chain feat pipeline: 3-group depth (load slot s at group s-3) ----
  // e: slot g (exp2 done); rb: slot g+1 raw; rc: slot g+2 raw in flight.
  float e0, e1, e2, e3, e4, e5, e6, e7;
  float rb0, rb1, rb2, rb3, rb4, rb5, rb6, rb7;
  float rc0, rc1, rc2, rc3, rc4, rc5, rc6, rc7;
  {
    float a0 = ldf(0), a1 = ldf(1), a2 = ldf(2), a3 = ldf(3),
          a4 = ldf(4), a5 = ldf(5), a6 = ldf(6), a7 = ldf(7);
    rb0 = ldf(8);  rb1 = ldf(9);  rb2 = ldf(10); rb3 = ldf(11);
    rb4 = ldf(12); rb5 = ldf(13); rb6 = ldf(14); rb7 = ldf(15);
    rc0 = ldf(16); rc1 = ldf(17); rc2 = ldf(18); rc3 = ldf(19);
    rc4 = ldf(20); rc5 = ldf(21); rc6 = ldf(22); rc7 = ldf(23);
    e0 = fexp2(a0 * L2E); e1 = fexp2(a1 * L2E); e2 = fexp2(a2 * L2E); e3 = fexp2(a3 * L2E);
    e4 = fexp2(a4 * L2E); e5 = fexp2(a5 * L2E); e6 = fexp2(a6 * L2E); e7 = fexp2(a7 * L2E);
  }

  int gi = 0;
  int k0 = 0;
  for (; k0 + 8 <= steps; k0 += 8, ++gi) {
    float rn0 = ldf(k0 + 24), rn1 = ldf(k0 + 25), rn2 = ldf(k0 + 26), rn3 = ldf(k0 + 27),
          rn4 = ldf(k0 + 28), rn5 = ldf(k0 + 29), rn6 = ldf(k0 + 30), rn7 = ldf(k0 + 31);
    GOLDG(gi)
    float x0 = fexp2(rb0 * L2E), x1 = fexp2(rb1 * L2E), x2 = fexp2(rb2 * L2E), x3 = fexp2(rb3 * L2E),
          x4 = fexp2(rb4 * L2E), x5 = fexp2(rb5 * L2E), x6 = fexp2(rb6 * L2E), x7 = fexp2(rb7 * L2E);
    STEP1(e0) STEP1(e1) STEP1(e2) STEP1(e3)
    RENORM
    STEP1(e4) STEP1(e5) STEP1(e6) STEP1(e7)
    RENORM
    e0 = x0; e1 = x1; e2 = x2; e3 = x3; e4 = x4; e5 = x5; e6 = x6; e7 = x7;
    rb0 = rc0; rb1 = rc1; rb2 = rc2; rb3 = rc3; rb4 = rc4; rb5 = rc5; rb6 = rc6; rb7 = rc7;
    rc0 = rn0; rc1 = rn1; rc2 = rn2; rc3 = rn3; rc4 = rn4; rc5 = rn5; rc6 = rn6; rc7 = rn7;
  }
  int r = steps - k0;
  if (r > 0) STEP1(e0)
  if (r > 1) STEP1(e1)
  if (r > 2) STEP1(e2)
  if (r > 3) STEP1(e3)
  if (r > 4) { RENORM STEP1(e4) }
  if (r > 5) STEP1(e5)
  if (r > 6) STEP1(e6)
  RENORM

  // gold pipeline drain: 5 groups cover all remaining slots for any steps
  for (int gd = 0; gd < 5; ++gd, ++gi) {
    GOLDG(gi)
  }

  if (act) outg[j] = g;
  if (j == 0) *outc = (float)cE;
  if (lane >= 32) sgold[(dir << 5) + li] = gs;

#undef GOLDG
#undef DOT24
#undef STEP1
#undef RENORM
}

// one block per batch: wave 0 = fwd chain + gold[t<min(len,1024)],
// wave 1 = bwd chain + gold[1024<=t<len]. Everything combined in-block.
__global__ __launch_bounds__(128) __attribute__((amdgpu_waves_per_eu(1, 2)))
void crf_chains(
    const float* __restrict__ feats, const float* __restrict__ trans,
    const int* __restrict__ tags, const int* __restrict__ lengths,
    float* __restrict__ ws)
{
  __shared__ float shg[2][NS];
  __shared__ float shc[2];
  __shared__ float sgold[64];
  const int b   = blockIdx.x;
  const int tid = threadIdx.x;
  const int dir = tid >> 6;
  const int lane = tid & 63;
  const int j   = lane;
  const int je  = (j < NS) ? j : (NS - 1);
  const int len = lengths[b];
  const int lenm1 = len - 1;
  const float* fb = feats + (size_t)b * (TLEN * NS);
  const int*   tg = tags  + (size_t)b * TLEN;

  const int ltag = tg[lenm1];   // for the STOP term (issued early, used at end)

  if (dir == 0) {
    int fsteps = (len < MID) ? len : MID;
    run_chain<false>(fb, trans, tg, fsteps, lenm1, lane, j, je, shg[0], &shc[0], sgold, 0);
  } else {
    int bsteps = (len > MID) ? (len - MID) : 0;
    run_chain<true>(fb, trans, tg, bsteps, lenm1, lane, j, je, shg[1], &shc[1], sgold, 1);
  }
  __syncthreads();

  if (tid < 32) {
    float prod = (tid < NS) ? shg[0][tid] * shg[1][tid] : 0.0f;
    float gtot = sgold[tid] + sgold[tid + 32];
    prod += SWZ(prod, 0x041F);  gtot += SWZ(gtot, 0x041F);
    prod += SWZ(prod, 0x081F);  gtot += SWZ(gtot, 0x081F);
    prod += SWZ(prod, 0x101F);  gtot += SWZ(gtot, 0x101F);
    prod += SWZ(prod, 0x201F);  gtot += SWZ(gtot, 0x201F);
    prod += SWZ(prod, 0x401F);  gtot += SWZ(gtot, 0x401F);
    if (tid == 0) {
      float alpha2 = shc[0] + shc[1] + flog2(prod);
      ws[b] = alpha2 * LN2F - (gtot + trans[KSTOP * NS + ltag]);
    }
  }
}

// mean over the 512 per-batch results
__global__ __launch_bounds__(256) void crf_final(const float* __restrict__ ws,
                                                 float* __restrict__ out)
{
  const int tid = threadIdx.x;
  float s = 0.0f;
  for (int i = tid; i < NBATCH; i += 256) s += ws[i];
  __shared__ float red[256];
  red[tid] = s;
  __syncthreads();
  for (int off = 128; off > 0; off >>= 1) {
    if (tid < off) red[tid] += red[tid + off];
    __syncthreads();
  }
  if (tid == 0) out[0] = red[0] * (1.0f / (float)NBATCH);
}

extern "C" void kernel_launch(void* const* d_in, const int* in_sizes, int n_in,
                              void* d_out, int out_size, void* d_ws, size_t ws_size,
                              hipStream_t stream) {
  const float* feats   = (const float*)d_in[0];
  const float* trans   = (const float*)d_in[1];
  const int*   tags    = (const int*)d_in[2];
  const int*   lengths = (const int*)d_in[3];
  float* out = (float*)d_out;
  float* ws  = (float*)d_ws;

  crf_chains<<<NBATCH, 128, 0, stream>>>(feats, trans, tags, lengths, ws);
  crf_final<<<1, 256, 0, stream>>>(ws, out);
}